// Round 1
// baseline (211.726 us; speedup 1.0000x reference)
//
#include <hip/hip_runtime.h>
#include <math.h>

// Router: logits = z @ W^T + b ; top-2 sparse softmax.  z:[8192,4096]f32,
// W:[64,4096]f32, b:[64], k=2.
//
// R10: kill the z-gather scatter. The MFMA A-frag layout forces lane (q,m)
// to read row m -> every prior z load was 64x16B pieces across 16 rows
// 16KB apart = TA request-rate wall (~5cyc/piece ~= the 76-86us plateau,
// invariant to pipeline depth, which is why R4-R9 all stalled there).
// Now z is staged global->LDS with fully-coalesced loads (each instr = 8
// rows x one complete 128B line) and frags come from ds_read_b128 (stride
// 36 f32 -> 2-way banks = free). Each wave stages ONLY its own 16 rows ->
// the z double-buffer is wave-private -> ZERO barriers in the main loop;
// per-wave counted vmcnt/lgkm waits are compiler-inserted. prep_w folded
// in (W f32->limb straight to LDS from L2-hot W). Epilogue transposes acc
// through the retired z-LDS region -> part stores are 4x contiguous 1KB.
// Precision identical to passing R5-R9: x = h + l*2^-11, 3 MFMA passes,
// recombine *2^-11. Frag layouts (verified R4-R8): A[m=lane&15][k=quad*8+j],
// B[n=lane&15][k=quad*8+j], D[row=quad*4+reg][col=lane&15].

typedef _Float16 f16x8 __attribute__((ext_vector_type(8)));
typedef _Float16 f16x4 __attribute__((ext_vector_type(4)));
typedef float    f32x4 __attribute__((ext_vector_type(4)));

constexpr int D_DIM  = 4096;
constexpr int K_DIM  = 64;
constexpr int BM     = 128;            // rows per block (8 waves x 16)
constexpr int KQ     = 16;             // split-K across blocks
constexpr int KRANGE = D_DIM / KQ;     // 256
constexpr int BLOCK  = 512;
constexpr int BSTR   = 264;            // W limb row stride in f16 (528 B)
constexpr int CH     = 32;             // z cols per chunk (one MFMA K-step)
constexpr int NCH    = KRANGE / CH;    // 8
constexpr int ZSTR   = 9;              // z row stride in f32x4 units (36 f32)

// ---- fused gemm: coalesced z->LDS dbuf (wave-private), W limbs inline ----
__global__ __launch_bounds__(BLOCK, 2) void gemm_fused(
    const float* __restrict__ z, const float* __restrict__ W,
    float* __restrict__ part, int N)
{
    __shared__ __align__(16) _Float16 Bs[2][K_DIM][BSTR];   // 67.6 KB
    __shared__ f32x4 zs[2][BM][ZSTR];                       // 36.9 KB

    const int tid  = threadIdx.x;
    const int lane = tid & 63;
    const int wv   = tid >> 6;          // 0..7 = m-tile (16 rows each)
    const int m16  = lane & 15;
    const int quad = lane >> 4;

    const int rgrp  = blockIdx.x >> 4;  // row group of 128
    const int kq    = blockIdx.x & 15;
    const long m0   = (long)rgrp * BM;
    const int kbase = kq * KRANGE;

    // staging coords: per instr, 8 rows x 8 units(16B) = 8 full 128B lines
    const int srow = wv * 16 + (lane >> 3);   // + t*8 (block-local row)
    const int su   = lane & 7;                // 16B unit within 32-col chunk
    const float* zb = z + m0 * D_DIM + kbase;

    // issue z chunk 0 (coalesced) so it flies under the W prep
    f32x4 zr[2];
#pragma unroll
    for (int t = 0; t < 2; ++t)
        zr[t] = *(const f32x4*)(zb + (long)(srow + t * 8) * D_DIM + su * 4);

    // W slice [64][256] f32 -> RNE hi/lo f16 limbs straight into LDS
#pragma unroll
    for (int i = 0; i < 8; ++i) {
        int idx = tid + i * BLOCK;           // 0..4095 float4s
        int row = idx >> 6, c4 = idx & 63;
        const f32x4 v = *(const f32x4*)(W + (long)row * D_DIM + kbase + c4 * 4);
        f16x4 h, l;
#pragma unroll
        for (int j = 0; j < 4; ++j) {
            _Float16 hh = (_Float16)v[j];
            h[j] = hh;
            l[j] = (_Float16)((v[j] - (float)hh) * 2048.0f);
        }
        *(f16x4*)&Bs[0][row][c4 * 4] = h;
        *(f16x4*)&Bs[1][row][c4 * 4] = l;
    }

    // park chunk 0 in the wave-private LDS region
#pragma unroll
    for (int t = 0; t < 2; ++t)
        zs[0][srow + t * 8][su] = zr[t];

    __syncthreads();                    // the ONLY barrier (W limbs visible)

    f32x4 acch[4], accl[4];
#pragma unroll
    for (int nt = 0; nt < 4; ++nt) {
        acch[nt] = (f32x4){0.f, 0.f, 0.f, 0.f};
        accl[nt] = (f32x4){0.f, 0.f, 0.f, 0.f};
    }

    const int zrow = wv * 16 + m16;
#pragma unroll
    for (int c = 0; c < NCH; ++c) {     // 8 K-steps, zero barriers
        if (c + 1 < NCH) {              // issue next chunk early (prefetch)
#pragma unroll
            for (int t = 0; t < 2; ++t)
                zr[t] = *(const f32x4*)(zb + (long)(srow + t * 8) * D_DIM
                                        + (c + 1) * CH + su * 4);
        }
        __builtin_amdgcn_sched_barrier(0);   // pin issue-early

        // A frag: 8 f32 of row zrow, cols c*32 + quad*8 .. +7 (2-way banks)
        const f32x4 a0 = zs[c & 1][zrow][quad * 2];
        const f32x4 a1 = zs[c & 1][zrow][quad * 2 + 1];
        f16x8 ah, al;
#pragma unroll
        for (int j = 0; j < 4; ++j) {   // exact RNE limb split (proven)
            _Float16 h0 = (_Float16)a0[j];
            ah[j]     = h0;
            al[j]     = (_Float16)((a0[j] - (float)h0) * 2048.0f);
            _Float16 h1 = (_Float16)a1[j];
            ah[j + 4] = h1;
            al[j + 4] = (_Float16)((a1[j] - (float)h1) * 2048.0f);
        }
        const int ko = c * 32 + quad * 8;
#pragma unroll
        for (int nt = 0; nt < 4; ++nt) {
            const f16x8 bh = *(const f16x8*)&Bs[0][nt * 16 + m16][ko];
            const f16x8 bl = *(const f16x8*)&Bs[1][nt * 16 + m16][ko];
            accl[nt] = __builtin_amdgcn_mfma_f32_16x16x32_f16(al, bh, accl[nt], 0, 0, 0);
            accl[nt] = __builtin_amdgcn_mfma_f32_16x16x32_f16(ah, bl, accl[nt], 0, 0, 0);
            acch[nt] = __builtin_amdgcn_mfma_f32_16x16x32_f16(ah, bh, acch[nt], 0, 0, 0);
        }

        if (c + 1 < NCH) {              // land prefetch in the other buffer
            __builtin_amdgcn_sched_barrier(0);   // keep writes after MFMAs
#pragma unroll
            for (int t = 0; t < 2; ++t)
                zs[(c + 1) & 1][srow + t * 8][su] = zr[t];
        }
    }

    // epilogue: transpose acc through retired z-LDS (wave-private, no bar),
    // then 4x fully-contiguous 1KB stores (4 complete part rows per instr).
    // rows 0-7 of the wave's 16 go in the zs[0] region, rows 8-15 in zs[1]
    // (each region is 16x36 f32 = 576 f32 >= 8 rows x stride 68).
    float* f0 = (float*)&zs[0][wv * 16][0];
    float* f1 = (float*)&zs[1][wv * 16][0];
#pragma unroll
    for (int nt = 0; nt < 4; ++nt) {
#pragma unroll
        for (int r = 0; r < 4; ++r) {
            float v = acch[nt][r] + accl[nt][r] * 4.8828125e-4f;
            float* base = (quad < 2) ? f0 : f1;
            base[((quad & 1) * 4 + r) * 68 + nt * 16 + m16] = v;   // 2-way banks
        }
    }
    const long prow0 = (long)kq * N + m0 + wv * 16;
#pragma unroll
    for (int t = 0; t < 4; ++t) {
        const float* base = (t < 2) ? f0 : f1;
        int lr8 = (t & 1) * 4 + (lane >> 4);          // row within region
        int c16 = (lane & 15) * 4;
        f32x4 v = *(const f32x4*)&base[lr8 * 68 + c16];
        int grow = t * 4 + (lane >> 4);               // row within wave tile
        *(f32x4*)(part + (prow0 + grow) * K_DIM + c16) = v;
    }
}

// ---- reduce + bias + top-2 + sparse softmax (unchanged, proven) ----------
constexpr int RG2  = 32;
constexpr int BLK2 = 256;

__global__ __launch_bounds__(BLK2) void reduce_topk(
    const float* __restrict__ part, const float* __restrict__ bias,
    float* __restrict__ out, int N)
{
    __shared__ float lg[RG2][K_DIM + 1];
    __shared__ float sa1[RG2], sa2[RG2];
    __shared__ int   si1[RG2], si2[RG2];

    const int tid = threadIdx.x;
    const long r0 = (long)blockIdx.x * RG2;

#pragma unroll
    for (int i = 0; i < (RG2 * K_DIM) / (BLK2 * 4); ++i) {       // 2 iters
        int f = tid + i * BLK2, r = f >> 4, c4 = (f & 15) * 4;
        float4 s = *(const float4*)(part + (r0 + r) * K_DIM + c4);
#pragma unroll
        for (int q = 1; q < KQ; ++q) {
            const float4 v = *(const float4*)(part + ((long)q * N + r0 + r) * K_DIM + c4);
            s.x += v.x; s.y += v.y; s.z += v.z; s.w += v.w;
        }
        const float4 bv = *(const float4*)(bias + c4);
        lg[r][c4 + 0] = s.x + bv.x;
        lg[r][c4 + 1] = s.y + bv.y;
        lg[r][c4 + 2] = s.z + bv.z;
        lg[r][c4 + 3] = s.w + bv.w;
    }
    __syncthreads();

    if (tid < RG2) {   // strict >, ascending scan = lowest-index tie-break
        float m1 = -INFINITY, m2 = -INFINITY;
        int i1 = 0, i2 = 0;
        for (int j = 0; j < K_DIM; ++j) {
            float v = lg[tid][j];
            if (v > m1)      { m2 = m1; i2 = i1; m1 = v; i1 = j; }
            else if (v > m2) { m2 = v; i2 = j; }
        }
        float e2  = expf(m2 - m1);
        float inv = 1.f / (1.f + e2);
        sa1[tid] = inv; sa2[tid] = e2 * inv;
        si1[tid] = i1;  si2[tid] = i2;
    }
    __syncthreads();

    float* obase = out + r0 * K_DIM;
#pragma unroll
    for (int i = 0; i < (RG2 * K_DIM) / (BLK2 * 4); ++i) {       // 2 iters
        int f = tid + i * BLK2, r = f >> 4, j = (f & 15) * 4;
        int i1 = si1[r], i2 = si2[r];
        float a1 = sa1[r], a2 = sa2[r];
        float4 v;
        v.x = (j + 0 == i1) ? a1 : ((j + 0 == i2) ? a2 : 0.f);
        v.y = (j + 1 == i1) ? a1 : ((j + 1 == i2) ? a2 : 0.f);
        v.z = (j + 2 == i1) ? a1 : ((j + 2 == i2) ? a2 : 0.f);
        v.w = (j + 3 == i1) ? a1 : ((j + 3 == i2) ? a2 : 0.f);
        *(float4*)(obase + (long)r * K_DIM + j) = v;
    }
}

extern "C" void kernel_launch(void* const* d_in, const int* in_sizes, int n_in,
                              void* d_out, int out_size, void* d_ws, size_t ws_size,
                              hipStream_t stream) {
    const float* z = (const float*)d_in[0];
    const float* W = (const float*)d_in[1];
    const float* b = (const float*)d_in[2];
    float* out  = (float*)d_out;
    const int N = in_sizes[0] / D_DIM;           // 8192

    float* part = (float*)d_ws;                  // 33.5 MB

    gemm_fused <<<dim3((N / BM) * KQ), dim3(BLOCK), 0, stream>>>(z, W, part, N);
    reduce_topk<<<dim3(N / RG2),       dim3(BLK2), 0, stream>>>(part, b, out, N);
}